// Round 3
// baseline (629.823 us; speedup 1.0000x reference)
//
#include <hip/hip_runtime.h>

#define NV 320
#define NB 32
#define NL 2048
#define ND 1024
#define DSPLIT 16                 // dim-slices per batch
#define DS (ND / DSPLIT)          // 64 dims per block (16 float4 lanes)

typedef float f32x4 __attribute__((ext_vector_type(4)));

// Fully fused, workspace-free kernel.
// grid = (DSPLIT, B) = 512 blocks, 256 threads.
// Each block: batch b, dims [ds*64, ds*64+64).
//   Phase 1: per-block LDS histogram of vq_indices[b] (redundant across the
//            16 dim-slices of a batch -- 16 KiB global read + 4K LDS atomics,
//            micro-seconds; buys full fusion and zero workspace).
//   Phase 2: prob[l] in LDS + block-reduced 1/sum.
//   Phase 3: masked weighted sum over feature rows, direct store to out.
__global__ __launch_bounds__(256) void vq_fused_kernel(
    const float* __restrict__ feature,    // (B, 2, L, D) f32
    const int*   __restrict__ lengths,    // (B,)
    const int*   __restrict__ vq_indices, // (B, L, 2) int32
    float*       __restrict__ out)        // (B, D)
{
    __shared__ int   cx[NV];
    __shared__ int   cy[NV];
    __shared__ float pl[NL];              // per-position prob (8 KiB)
    __shared__ f32x4 sred[16][16];        // cross-group reduction (4 KiB)
    __shared__ float wave_sums[4];
    __shared__ float sinv;

    const int ds = blockIdx.x;
    const int b  = blockIdx.y;
    const int t  = threadIdx.x;
    const int len = lengths[b];

    for (int i = t; i < NV; i += 256) { cx[i] = 0; cy[i] = 0; }
    __syncthreads();

    // ---- Phase 1: histogram over ALL L positions (reference is unmasked).
    // 1024 int4 per batch; 4 per thread, kept in registers for phase 2.
    const int4* idx4 = (const int4*)(vq_indices) + (size_t)b * (NL / 2);
    int4 r[4];
    #pragma unroll
    for (int k = 0; k < 4; ++k) {
        r[k] = idx4[t + k * 256];         // (x0,y0,x1,y1)
        atomicAdd(&cx[r[k].x], 1);
        atomicAdd(&cy[r[k].y], 1);
        atomicAdd(&cx[r[k].z], 1);
        atomicAdd(&cy[r[k].w], 1);
    }
    __syncthreads();

    // ---- Phase 2: prob into LDS, masked sum -> 1/sum.
    float local = 0.f;
    #pragma unroll
    for (int k = 0; k < 4; ++k) {
        const int i  = t + k * 256;       // pair index; positions 2i, 2i+1
        const int la = 2 * i, lb = 2 * i + 1;
        float pa = (la < len) ? 1.0f / (float)(cx[r[k].x] + cy[r[k].y]) : 0.f;
        float pb = (lb < len) ? 1.0f / (float)(cx[r[k].z] + cy[r[k].w]) : 0.f;
        pl[la] = pa;
        pl[lb] = pb;
        local += pa + pb;
    }
    for (int off = 32; off > 0; off >>= 1)
        local += __shfl_down(local, off, 64);
    if ((t & 63) == 0) wave_sums[t >> 6] = local;
    __syncthreads();                      // pl[] and wave_sums[] complete
    if (t == 0)
        sinv = 1.0f / (wave_sums[0] + wave_sums[1] + wave_sums[2] + wave_sums[3]);

    // ---- Phase 3: weighted sum over masked rows.
    // thread t: lane = t&15 (float4 within dim slice), grp = t>>4 (row group).
    const int lane = t & 15;
    const int grp  = t >> 4;

    const f32x4* f4 = (const f32x4*)(feature + ((size_t)b * 2 + 1) * (size_t)NL * ND);
    const size_t colbase = (size_t)ds * (DS / 4) + lane;

    f32x4 acc = {0.f, 0.f, 0.f, 0.f};
    for (int l = grp; l < len; l += 16) {
        float w  = pl[l];                                        // LDS broadcast per group
        f32x4 v  = __builtin_nontemporal_load(&f4[(size_t)l * (ND / 4) + colbase]);
        acc += w * v;
    }

    sred[grp][lane] = acc;
    __syncthreads();                      // sred complete; sinv visible

    if (t < 16) {
        f32x4 s = {0.f, 0.f, 0.f, 0.f};
        #pragma unroll
        for (int g = 0; g < 16; ++g)
            s += sred[g][t];
        s *= sinv;
        ((f32x4*)(out + (size_t)b * ND + (size_t)ds * DS))[t] = s;
    }
}

extern "C" void kernel_launch(void* const* d_in, const int* in_sizes, int n_in,
                              void* d_out, int out_size, void* d_ws, size_t ws_size,
                              hipStream_t stream) {
    const float* feature = (const float*)d_in[0];   // (B, 2, L, D) f32
    const int*   lengths = (const int*)d_in[1];     // (B,) int
    const int*   vq      = (const int*)d_in[2];     // (B, L, 2) int
    float* out = (float*)d_out;

    // No workspace use, no memset, no atomics-to-global: out is written
    // fully and deterministically by exactly one thread per element.
    (void)d_ws; (void)ws_size;

    vq_fused_kernel<<<dim3(DSPLIT, NB), 256, 0, stream>>>(feature, lengths, vq, out);
}